// Round 2
// baseline (428.534 us; speedup 1.0000x reference)
//
#include <hip/hip_runtime.h>

#define RES  128
#define FEAT 1024   // map_num(128) * feat_dim(8)

__global__ __launch_bounds__(256)
void DenseMap_kernel(const float* __restrict__ inputs,
                     const float* __restrict__ emb,
                     float* __restrict__ out)
{
    const int p = blockIdx.x;     // point index
    const int c = threadIdx.x;    // float4 chunk index, 0..255

    // Wave-uniform per-point setup (compiler scalarizes: blockIdx-uniform addr)
    const float x0 = inputs[2 * p + 0] * (float)(RES - 1);
    const float x1 = inputs[2 * p + 1] * (float)(RES - 1);
    const float f0 = floorf(x0);
    const float f1 = floorf(x1);
    const int   i0 = (int)f0;
    const int   i1 = (int)f1;
    const float xf0 = x0 - f0;
    const float xf1 = x1 - f1;

    // bin_mask semantics: n=0 -> (i0,i1) w=(1-xf0)(1-xf1); n=1 -> (i0+1,i1) w=xf0(1-xf1)
    //                     n=2 -> (i0,i1+1) w=(1-xf0)xf1;   n=3 -> (i0+1,i1+1) w=xf0*xf1
    const float w00 = (1.0f - xf0) * (1.0f - xf1);
    const float w01 = (1.0f - xf0) * xf1;
    const float w10 = xf0 * (1.0f - xf1);
    const float w11 = xf0 * xf1;

    const long base = (long)(i0 * RES + i1) * FEAT;
    const float4* e00 = (const float4*)(emb + base) + c;
    const float4* e01 = (const float4*)(emb + base + FEAT) + c;
    const float4* e10 = (const float4*)(emb + base + (long)RES * FEAT) + c;
    const float4* e11 = (const float4*)(emb + base + (long)RES * FEAT + FEAT) + c;

    const float4 a = *e00;
    const float4 b = *e01;
    const float4 g = *e10;
    const float4 h = *e11;

    float4 r;
    r.x = a.x * w00 + b.x * w01 + g.x * w10 + h.x * w11;
    r.y = a.y * w00 + b.y * w01 + g.y * w10 + h.y * w11;
    r.z = a.z * w00 + b.z * w01 + g.z * w10 + h.z * w11;
    r.w = a.w * w00 + b.w * w01 + g.w * w10 + h.w * w11;

    ((float4*)(out + (long)p * FEAT))[c] = r;
}

extern "C" void kernel_launch(void* const* d_in, const int* in_sizes, int n_in,
                              void* d_out, int out_size, void* d_ws, size_t ws_size,
                              hipStream_t stream)
{
    const float* inputs = (const float*)d_in[0];   // (batch, 2) fp32
    const float* emb    = (const float*)d_in[1];   // (16384, 1024) fp32
    float*       out    = (float*)d_out;           // (batch, 1024) fp32

    const int batch = in_sizes[0] / 2;             // 65536
    DenseMap_kernel<<<batch, 256, 0, stream>>>(inputs, emb, out);
}

// Round 3
// 388.606 us; speedup vs baseline: 1.1027x; 1.1027x over previous
//
#include <hip/hip_runtime.h>

#define RES   128
#define FEAT  1024   // map_num(128) * feat_dim(8)
#define NBINS (RES * RES)

// ---------------------------------------------------------------------------
// Pass B: histogram points per grid cell
__global__ __launch_bounds__(256)
void hist_kernel(const float* __restrict__ inputs, unsigned* __restrict__ hist, int N)
{
    int p = blockIdx.x * 256 + threadIdx.x;
    if (p >= N) return;
    int i0 = (int)floorf(inputs[2 * p + 0] * (float)(RES - 1));
    int i1 = (int)floorf(inputs[2 * p + 1] * (float)(RES - 1));
    atomicAdd(&hist[i0 * RES + i1], 1u);
}

// ---------------------------------------------------------------------------
// Pass C: in-place exclusive scan of 16384 bins (single block, 256 thr x 64)
__global__ __launch_bounds__(256)
void scan_kernel(unsigned* __restrict__ hist)
{
    __shared__ unsigned part[256];
    int t = threadIdx.x;
    int base = t * 64;
    unsigned s = 0;
    for (int k = 0; k < 64; ++k) s += hist[base + k];
    part[t] = s;
    __syncthreads();
    if (t == 0) {
        unsigned run = 0;
        for (int i = 0; i < 256; ++i) { unsigned v = part[i]; part[i] = run; run += v; }
    }
    __syncthreads();
    unsigned run = part[t];
    for (int k = 0; k < 64; ++k) { unsigned v = hist[base + k]; hist[base + k] = run; run += v; }
}

// ---------------------------------------------------------------------------
// Pass D: scatter point indices into cell-sorted order
__global__ __launch_bounds__(256)
void scatter_kernel(const float* __restrict__ inputs, unsigned* __restrict__ hist,
                    unsigned* __restrict__ order, int N)
{
    int p = blockIdx.x * 256 + threadIdx.x;
    if (p >= N) return;
    int i0 = (int)floorf(inputs[2 * p + 0] * (float)(RES - 1));
    int i1 = (int)floorf(inputs[2 * p + 1] * (float)(RES - 1));
    unsigned pos = atomicAdd(&hist[i0 * RES + i1], 1u);
    order[pos] = (unsigned)p;
}

// ---------------------------------------------------------------------------
// Pass E: bilinear gather-blend in sorted order, 4 points/block,
// XCD-aware swizzle: block b -> XCD (b%8) processes a contiguous sorted chunk.
__global__ __launch_bounds__(256)
void DenseMap_sorted_kernel(const float* __restrict__ inputs,
                            const float* __restrict__ emb,
                            const unsigned* __restrict__ order,
                            float* __restrict__ out,
                            int N, int chunk)
{
    const int b = blockIdx.x;
    const int c = threadIdx.x;
    // chunk>0: G divisible by 8 -> swizzled contiguous chunks per XCD
    const int g = (chunk > 0) ? ((b & 7) * chunk + (b >> 3)) : b;

#pragma unroll
    for (int j = 0; j < 4; ++j) {
        const int s = g * 4 + j;
        if (s >= N) break;
        const int p = (int)order[s];

        const float x0 = inputs[2 * p + 0] * (float)(RES - 1);
        const float x1 = inputs[2 * p + 1] * (float)(RES - 1);
        const float f0 = floorf(x0);
        const float f1 = floorf(x1);
        const int   i0 = (int)f0;
        const int   i1 = (int)f1;
        const float xf0 = x0 - f0;
        const float xf1 = x1 - f1;

        const float w00 = (1.0f - xf0) * (1.0f - xf1);
        const float w01 = (1.0f - xf0) * xf1;
        const float w10 = xf0 * (1.0f - xf1);
        const float w11 = xf0 * xf1;

        const long base = (long)(i0 * RES + i1) * FEAT;
        const float4 a = ((const float4*)(emb + base))[c];
        const float4 bb = ((const float4*)(emb + base + FEAT))[c];
        const float4 gg = ((const float4*)(emb + base + (long)RES * FEAT))[c];
        const float4 h = ((const float4*)(emb + base + (long)RES * FEAT + FEAT))[c];

        float4 r;
        r.x = a.x * w00 + bb.x * w01 + gg.x * w10 + h.x * w11;
        r.y = a.y * w00 + bb.y * w01 + gg.y * w10 + h.y * w11;
        r.z = a.z * w00 + bb.z * w01 + gg.z * w10 + h.z * w11;
        r.w = a.w * w00 + bb.w * w01 + gg.w * w10 + h.w * w11;

        ((float4*)(out + (long)p * FEAT))[c] = r;
    }
}

// ---------------------------------------------------------------------------
// Fallback (R2 kernel): used only if ws is too small for the sort buffers.
__global__ __launch_bounds__(256)
void DenseMap_fallback_kernel(const float* __restrict__ inputs,
                              const float* __restrict__ emb,
                              float* __restrict__ out)
{
    const int p = blockIdx.x;
    const int c = threadIdx.x;

    const float x0 = inputs[2 * p + 0] * (float)(RES - 1);
    const float x1 = inputs[2 * p + 1] * (float)(RES - 1);
    const float f0 = floorf(x0);
    const float f1 = floorf(x1);
    const int   i0 = (int)f0;
    const int   i1 = (int)f1;
    const float xf0 = x0 - f0;
    const float xf1 = x1 - f1;

    const float w00 = (1.0f - xf0) * (1.0f - xf1);
    const float w01 = (1.0f - xf0) * xf1;
    const float w10 = xf0 * (1.0f - xf1);
    const float w11 = xf0 * xf1;

    const long base = (long)(i0 * RES + i1) * FEAT;
    const float4 a = ((const float4*)(emb + base))[c];
    const float4 b = ((const float4*)(emb + base + FEAT))[c];
    const float4 g = ((const float4*)(emb + base + (long)RES * FEAT))[c];
    const float4 h = ((const float4*)(emb + base + (long)RES * FEAT + FEAT))[c];

    float4 r;
    r.x = a.x * w00 + b.x * w01 + g.x * w10 + h.x * w11;
    r.y = a.y * w00 + b.y * w01 + g.y * w10 + h.y * w11;
    r.z = a.z * w00 + b.z * w01 + g.z * w10 + h.z * w11;
    r.w = a.w * w00 + b.w * w01 + g.w * w10 + h.w * w11;

    ((float4*)(out + (long)p * FEAT))[c] = r;
}

extern "C" void kernel_launch(void* const* d_in, const int* in_sizes, int n_in,
                              void* d_out, int out_size, void* d_ws, size_t ws_size,
                              hipStream_t stream)
{
    const float* inputs = (const float*)d_in[0];   // (batch, 2) fp32
    const float* emb    = (const float*)d_in[1];   // (16384, 1024) fp32
    float*       out    = (float*)d_out;           // (batch, 1024) fp32

    const int N = in_sizes[0] / 2;                 // 65536
    const size_t need = (size_t)(NBINS + N) * sizeof(unsigned);

    if (ws_size >= need) {
        unsigned* hist  = (unsigned*)d_ws;         // [NBINS]
        unsigned* order = hist + NBINS;            // [N]

        hipMemsetAsync(hist, 0, NBINS * sizeof(unsigned), stream);
        hist_kernel<<<(N + 255) / 256, 256, 0, stream>>>(inputs, hist, N);
        scan_kernel<<<1, 256, 0, stream>>>(hist);
        scatter_kernel<<<(N + 255) / 256, 256, 0, stream>>>(inputs, hist, order, N);

        const int G = (N + 3) / 4;                 // groups of 4 points
        const int chunk = (G % 8 == 0) ? (G / 8) : 0;
        DenseMap_sorted_kernel<<<G, 256, 0, stream>>>(inputs, emb, order, out, N, chunk);
    } else {
        DenseMap_fallback_kernel<<<N, 256, 0, stream>>>(inputs, emb, out);
    }
}